// Round 2
// baseline (698.002 us; speedup 1.0000x reference)
//
#include <hip/hip_runtime.h>
#include <hip/hip_bf16.h>

#define B_ 256
#define T_ 512
#define V_ 30000
#define E_ 256
#define H_ 32

// ---------------------------------------------------------------------------
// Fast activations (fp32, monotone-safe at extremes: no NaN, saturate to 0/1/±1)
// ---------------------------------------------------------------------------
__device__ __forceinline__ float sigmoidf_fast(float x) {
    return 1.0f / (1.0f + __expf(-x));
}
__device__ __forceinline__ float tanhf_fast(float x) {
    // 1 - 2/(1+exp(2x)); exp overflow -> inf -> result 1; underflow -> -1
    return 1.0f - 2.0f / (1.0f + __expf(2.0f * x));
}
__device__ __forceinline__ float rl(float v, int lane) {
    return __int_as_float(__builtin_amdgcn_readlane(__float_as_int(v), lane));
}

// ---------------------------------------------------------------------------
// GEMM: Out[M,192] = A[M,K] @ Wcat[192,K]^T + bias   (unchanged from R1)
// ---------------------------------------------------------------------------
#define GEMM_MT 64
#define GEMM_KC 32
#define GEMM_PA 68
#define GEMM_PB 196

__global__ __launch_bounds__(256) void gemm_gates(
    const float* __restrict__ A, int M, int K,
    const float* __restrict__ Wf, const float* __restrict__ Wb,
    const float* __restrict__ bihf, const float* __restrict__ bhhf,
    const float* __restrict__ bihb, const float* __restrict__ bhhb,
    float* __restrict__ Out)
{
    __shared__ float As[GEMM_KC][GEMM_PA];   // k-major, padded
    __shared__ float Bs[GEMM_KC][GEMM_PB];

    const int tid = threadIdx.x;
    const int mbase = blockIdx.x * GEMM_MT;
    const int mg = tid >> 5, ng = tid & 31;
    const int m_off = mg * 8, n_off = ng * 6;

    float acc[8][6];
    #pragma unroll
    for (int r = 0; r < 8; ++r)
        #pragma unroll
        for (int c = 0; c < 6; ++c) acc[r][c] = 0.f;

    for (int kc = 0; kc < K; kc += GEMM_KC) {
        #pragma unroll
        for (int i = 0; i < 2; ++i) {
            int fi = tid + 256 * i;
            int row = fi >> 3, cf = fi & 7;
            int m = mbase + row;
            float4 v = make_float4(0.f, 0.f, 0.f, 0.f);
            if (m < M) v = *(const float4*)&A[(size_t)m * K + kc + cf * 4];
            As[cf * 4 + 0][row] = v.x; As[cf * 4 + 1][row] = v.y;
            As[cf * 4 + 2][row] = v.z; As[cf * 4 + 3][row] = v.w;
        }
        #pragma unroll
        for (int i = 0; i < 6; ++i) {
            int fi = tid + 256 * i;
            int g = fi >> 3, cf = fi & 7;
            const float* Wsel = (g < 96) ? (Wf + (size_t)g * K)
                                         : (Wb + (size_t)(g - 96) * K);
            float4 v = *(const float4*)&Wsel[kc + cf * 4];
            Bs[cf * 4 + 0][g] = v.x; Bs[cf * 4 + 1][g] = v.y;
            Bs[cf * 4 + 2][g] = v.z; Bs[cf * 4 + 3][g] = v.w;
        }
        __syncthreads();
        #pragma unroll
        for (int k = 0; k < GEMM_KC; ++k) {
            float a[8], bb[6];
            *(float4*)&a[0] = *(const float4*)&As[k][m_off];
            *(float4*)&a[4] = *(const float4*)&As[k][m_off + 4];
            *(float2*)&bb[0] = *(const float2*)&Bs[k][n_off];
            *(float2*)&bb[2] = *(const float2*)&Bs[k][n_off + 2];
            *(float2*)&bb[4] = *(const float2*)&Bs[k][n_off + 4];
            #pragma unroll
            for (int r = 0; r < 8; ++r)
                #pragma unroll
                for (int c = 0; c < 6; ++c)
                    acc[r][c] = fmaf(a[r], bb[c], acc[r][c]);
        }
        __syncthreads();
    }

    float bias[6];
    #pragma unroll
    for (int c = 0; c < 6; ++c) {
        int g = n_off + c;
        int g96 = (g < 96) ? g : g - 96;
        const float* bih = (g < 96) ? bihf : bihb;
        const float* bhh = (g < 96) ? bhhf : bhhb;
        bias[c] = bih[g96] + ((g96 < 64) ? bhh[g96] : 0.f);
    }
    #pragma unroll
    for (int r = 0; r < 8; ++r) {
        int m = mbase + m_off + r;
        if (m < M) {
            float* op = &Out[(size_t)m * 192 + n_off];
            #pragma unroll
            for (int c = 0; c < 6; ++c) op[c] = acc[r][c] + bias[c];
        }
    }
}

// ---------------------------------------------------------------------------
// GRU scan: one wave per (batch, direction). h[j] in lane j (j<32), broadcast
// via v_readlane. Lane l<32 computes gates r,n; lane l>=32 computes z (same
// instructions, different per-lane weight rows); z crosses halves via one
// __shfl_xor. 2-step-deep prefetch pipeline for gi/mask (4-deep for ids).
// __launch_bounds__(64,1): grid-limited occupancy; give allocator the full
// VGPR budget so wA/wB (64 floats/lane) stay in arch VGPRs.
// ---------------------------------------------------------------------------
__global__ __launch_bounds__(64, 1) void gru_scan(
    const float* __restrict__ gi,     // [rows,192]: G0 gather or gi1 direct
    const int* __restrict__ ids,      // used when use_ids != 0
    const int* __restrict__ mask,     // [B,T] int
    const float* __restrict__ Whh_f, const float* __restrict__ Whh_b,
    const float* __restrict__ bhh_f, const float* __restrict__ bhh_b,
    float* __restrict__ out_seq,      // [B,T,64] or nullptr
    float* __restrict__ out_fin,      // [B,64]   or nullptr
    int use_ids)
{
    const int l = threadIdx.x;
    const int j = l & 31;
    const bool lower = l < 32;
    const int dir = blockIdx.x & 1;
    const int b = blockIdx.x >> 1;
    const int bT = b * T_;
    const int dt = dir ? -1 : 1;
    const int t0 = dir ? (T_ - 1) : 0;

    const float* Whh = dir ? Whh_b : Whh_f;
    const float* bhh = dir ? bhh_b : bhh_f;

    // weight rows into registers (float4 loads)
    const int rowA = lower ? j : (32 + j);  // r-row (lower) / z-row (upper)
    float wA[32], wB[32];
    #pragma unroll
    for (int q = 0; q < 8; ++q) {
        float4 a = *(const float4*)&Whh[rowA * 32 + q * 4];
        wA[q * 4 + 0] = a.x; wA[q * 4 + 1] = a.y;
        wA[q * 4 + 2] = a.z; wA[q * 4 + 3] = a.w;
        float4 bq = *(const float4*)&Whh[(64 + j) * 32 + q * 4];
        wB[q * 4 + 0] = bq.x; wB[q * 4 + 1] = bq.y;
        wB[q * 4 + 2] = bq.z; wB[q * 4 + 3] = bq.w;
    }
    const float bn = bhh[64 + j];

    // step index -> clamped t (prefetch beyond the end reads a valid row)
    auto tclamp = [&](int i) -> int {
        int t = t0 + dt * i;
        return t < 0 ? 0 : (t > T_ - 1 ? T_ - 1 : t);
    };

    // ---- prefetch pipeline prologue ----
    const int ta = tclamp(0), tb = tclamp(1), tc = tclamp(2), td = tclamp(3);
    int idA, idB, id2, id3;
    if (use_ids) {
        idA = ids[bT + ta]; idB = ids[bT + tb];
        id2 = ids[bT + tc]; id3 = ids[bT + td];
    } else {
        idA = bT + ta; idB = bT + tb; id2 = bT + tc; id3 = bT + td;
    }
    const float* gpA = gi + (size_t)idA * 192 + dir * 96;
    float gA0 = gpA[l], gB0 = gpA[64 + j];
    const float* gpB = gi + (size_t)idB * 192 + dir * 96;
    float gA1 = gpB[l], gB1 = gpB[64 + j];
    int m0 = mask[bT + ta], m1 = mask[bT + tb];

    float h = 0.f;
    float* outp = out_seq ? (out_seq + (size_t)(bT + t0) * 64 + dir * 32 + j)
                          : nullptr;
    const long long outstep = (long long)dt * 64;

    for (int i = 0; i < T_; ++i) {
        // ---- issue prefetch for step i+2 (and ids for i+4) ----
        const int t2 = tclamp(i + 2);
        const int r2 = use_ids ? id2 : (bT + t2);
        const float* gp2 = gi + (size_t)r2 * 192 + dir * 96;
        const float gA2 = gp2[l];
        const float gB2 = gp2[64 + j];
        const int mN = mask[bT + t2];
        const int id4 = use_ids ? ids[bT + tclamp(i + 4)] : 0;

        // ---- recurrent matvec via readlane broadcast, 4-way split chains ----
        float aA0 = 0.f, aA1 = 0.f, aA2 = 0.f, aA3 = 0.f;
        float aB0 = 0.f, aB1 = 0.f, aB2 = 0.f, aB3 = 0.f;
        #pragma unroll
        for (int k = 0; k < 32; k += 4) {
            const float h0 = rl(h, k);
            const float h1 = rl(h, k + 1);
            const float h2 = rl(h, k + 2);
            const float h3 = rl(h, k + 3);
            aA0 = fmaf(wA[k],     h0, aA0);  aB0 = fmaf(wB[k],     h0, aB0);
            aA1 = fmaf(wA[k + 1], h1, aA1);  aB1 = fmaf(wB[k + 1], h1, aB1);
            aA2 = fmaf(wA[k + 2], h2, aA2);  aB2 = fmaf(wB[k + 2], h2, aB2);
            aA3 = fmaf(wA[k + 3], h3, aA3);  aB3 = fmaf(wB[k + 3], h3, aB3);
        }
        const float dA = (aA0 + aA1) + (aA2 + aA3);
        const float dB = (aB0 + aB1) + (aB2 + aB3);

        const float s  = sigmoidf_fast(gA0 + dA); // r (lower) / z (upper)
        const float hn = bn + dB;                 // h·Whh_n + bhh_n
        const float zz = __shfl_xor(s, 32, 64);   // lower lanes receive z
        const float n  = tanhf_fast(gB0 + s * hn);
        const float hnew = n + zz * (h - n);      // (1-z)n + z h
        h = m0 ? hnew : h;                        // packed-seq freeze

        if (outp != nullptr && lower) *outp = h;
        if (outp != nullptr) outp += outstep;

        // ---- shift pipeline ----
        gA0 = gA1; gB0 = gB1; gA1 = gA2; gB1 = gB2;
        m0 = m1;   m1 = mN;   id2 = id3; id3 = id4;
    }

    if (out_fin != nullptr && lower)
        out_fin[b * 64 + dir * 32 + j] = h;
}

// ---------------------------------------------------------------------------
// Head: out[b,o] = hfin[b,:] . Wout[o,:] + bout[o]   (tiny)
// ---------------------------------------------------------------------------
__global__ void head_kernel(const float* __restrict__ hfin,
                            const float* __restrict__ Wout,
                            const float* __restrict__ bout,
                            float* __restrict__ out)
{
    int idx = blockIdx.x * blockDim.x + threadIdx.x;
    if (idx >= B_ * 6) return;
    int b = idx / 6, o = idx % 6;
    float acc = bout[o];
    const float* hp = hfin + b * 64;
    const float* wp = Wout + o * 64;
    #pragma unroll
    for (int k = 0; k < 64; ++k) acc = fmaf(hp[k], wp[k], acc);
    out[idx] = acc;
}

// ---------------------------------------------------------------------------
extern "C" void kernel_launch(void* const* d_in, const int* in_sizes, int n_in,
                              void* d_out, int out_size, void* d_ws, size_t ws_size,
                              hipStream_t stream)
{
    const int*   ids   = (const int*)d_in[0];
    const int*   mask  = (const int*)d_in[1];
    const float* embed = (const float*)d_in[2];
    const float* Wih0f = (const float*)d_in[3];
    const float* Whh0f = (const float*)d_in[4];
    const float* bih0f = (const float*)d_in[5];
    const float* bhh0f = (const float*)d_in[6];
    const float* Wih0b = (const float*)d_in[7];
    const float* Whh0b = (const float*)d_in[8];
    const float* bih0b = (const float*)d_in[9];
    const float* bhh0b = (const float*)d_in[10];
    const float* Wih1f = (const float*)d_in[11];
    const float* Whh1f = (const float*)d_in[12];
    const float* bih1f = (const float*)d_in[13];
    const float* bhh1f = (const float*)d_in[14];
    const float* Wih1b = (const float*)d_in[15];
    const float* Whh1b = (const float*)d_in[16];
    const float* bih1b = (const float*)d_in[17];
    const float* bhh1b = (const float*)d_in[18];
    const float* Wout  = (const float*)d_in[19];
    const float* bout  = (const float*)d_in[20];

    // workspace layout (floats):
    //   [0, 25165824)              gbuf : G0 [V,192] (K1,K2) then gi1 [B*T,192] (K3,K4)
    //   [25165824, 33554432)       x1   : [B,T,64]
    //   [33554432, 33570816)       hfin : [B,64]
    float* ws   = (float*)d_ws;
    float* gbuf = ws;
    float* x1   = ws + (size_t)B_ * T_ * 192;
    float* hfin = x1 + (size_t)B_ * T_ * 64;

    // K1: vocab-factored layer-0 input gates  G0 = embed @ Wcat0^T + bias
    gemm_gates<<<(V_ + GEMM_MT - 1) / GEMM_MT, 256, 0, stream>>>(
        embed, V_, E_, Wih0f, Wih0b, bih0f, bhh0f, bih0b, bhh0b, gbuf);

    // K2: layer-0 bidirectional scan (gathers G0[id]), writes x1
    gru_scan<<<2 * B_, 64, 0, stream>>>(
        gbuf, ids, mask, Whh0f, Whh0b, bhh0f, bhh0b, x1, nullptr, 1);

    // K3: layer-1 input gates  gi1 = x1 @ Wcat1^T + bias  (overwrites dead G0)
    gemm_gates<<<(B_ * T_) / GEMM_MT, 256, 0, stream>>>(
        x1, B_ * T_, 64, Wih1f, Wih1b, bih1f, bhh1f, bih1b, bhh1b, gbuf);

    // K4: layer-1 scan, final hiddens only
    gru_scan<<<2 * B_, 64, 0, stream>>>(
        gbuf, nullptr, mask, Whh1f, Whh1b, bhh1f, bhh1b, nullptr, hfin, 0);

    // K5: output head
    head_kernel<<<(B_ * 6 + 255) / 256, 256, 0, stream>>>(hfin, Wout, bout,
                                                          (float*)d_out);
}

// Round 3
// 577.446 us; speedup vs baseline: 1.2088x; 1.2088x over previous
//
#include <hip/hip_runtime.h>
#include <hip/hip_bf16.h>

#define B_ 256
#define T_ 512
#define V_ 30000
#define E_ 256
#define H_ 32

// ---------------------------------------------------------------------------
// Fast activations (fp32, saturate cleanly at extremes: no NaN)
// ---------------------------------------------------------------------------
__device__ __forceinline__ float sigmoidf_fast(float x) {
    return 1.0f / (1.0f + __expf(-x));
}
__device__ __forceinline__ float tanhf_fast(float x) {
    return 1.0f - 2.0f / (1.0f + __expf(2.0f * x));
}
__device__ __forceinline__ float rl(float v, int lane) {
    return __int_as_float(__builtin_amdgcn_readlane(__float_as_int(v), lane));
}

// ---------------------------------------------------------------------------
// GEMM: Out[M,192] = A[M,K] @ Wcat[192,K]^T + bias   (unchanged from R1)
// ---------------------------------------------------------------------------
#define GEMM_MT 64
#define GEMM_KC 32
#define GEMM_PA 68
#define GEMM_PB 196

__global__ __launch_bounds__(256) void gemm_gates(
    const float* __restrict__ A, int M, int K,
    const float* __restrict__ Wf, const float* __restrict__ Wb,
    const float* __restrict__ bihf, const float* __restrict__ bhhf,
    const float* __restrict__ bihb, const float* __restrict__ bhhb,
    float* __restrict__ Out)
{
    __shared__ float As[GEMM_KC][GEMM_PA];
    __shared__ float Bs[GEMM_KC][GEMM_PB];

    const int tid = threadIdx.x;
    const int mbase = blockIdx.x * GEMM_MT;
    const int mg = tid >> 5, ng = tid & 31;
    const int m_off = mg * 8, n_off = ng * 6;

    float acc[8][6];
    #pragma unroll
    for (int r = 0; r < 8; ++r)
        #pragma unroll
        for (int c = 0; c < 6; ++c) acc[r][c] = 0.f;

    for (int kc = 0; kc < K; kc += GEMM_KC) {
        #pragma unroll
        for (int i = 0; i < 2; ++i) {
            int fi = tid + 256 * i;
            int row = fi >> 3, cf = fi & 7;
            int m = mbase + row;
            float4 v = make_float4(0.f, 0.f, 0.f, 0.f);
            if (m < M) v = *(const float4*)&A[(size_t)m * K + kc + cf * 4];
            As[cf * 4 + 0][row] = v.x; As[cf * 4 + 1][row] = v.y;
            As[cf * 4 + 2][row] = v.z; As[cf * 4 + 3][row] = v.w;
        }
        #pragma unroll
        for (int i = 0; i < 6; ++i) {
            int fi = tid + 256 * i;
            int g = fi >> 3, cf = fi & 7;
            const float* Wsel = (g < 96) ? (Wf + (size_t)g * K)
                                         : (Wb + (size_t)(g - 96) * K);
            float4 v = *(const float4*)&Wsel[kc + cf * 4];
            Bs[cf * 4 + 0][g] = v.x; Bs[cf * 4 + 1][g] = v.y;
            Bs[cf * 4 + 2][g] = v.z; Bs[cf * 4 + 3][g] = v.w;
        }
        __syncthreads();
        #pragma unroll
        for (int k = 0; k < GEMM_KC; ++k) {
            float a[8], bb[6];
            *(float4*)&a[0] = *(const float4*)&As[k][m_off];
            *(float4*)&a[4] = *(const float4*)&As[k][m_off + 4];
            *(float2*)&bb[0] = *(const float2*)&Bs[k][n_off];
            *(float2*)&bb[2] = *(const float2*)&Bs[k][n_off + 2];
            *(float2*)&bb[4] = *(const float2*)&Bs[k][n_off + 4];
            #pragma unroll
            for (int r = 0; r < 8; ++r)
                #pragma unroll
                for (int c = 0; c < 6; ++c)
                    acc[r][c] = fmaf(a[r], bb[c], acc[r][c]);
        }
        __syncthreads();
    }

    float bias[6];
    #pragma unroll
    for (int c = 0; c < 6; ++c) {
        int g = n_off + c;
        int g96 = (g < 96) ? g : g - 96;
        const float* bih = (g < 96) ? bihf : bihb;
        const float* bhh = (g < 96) ? bhhf : bhhb;
        bias[c] = bih[g96] + ((g96 < 64) ? bhh[g96] : 0.f);
    }
    #pragma unroll
    for (int r = 0; r < 8; ++r) {
        int m = mbase + m_off + r;
        if (m < M) {
            float* op = &Out[(size_t)m * 192 + n_off];
            #pragma unroll
            for (int c = 0; c < 6; ++c) op[c] = acc[r][c] + bias[c];
        }
    }
}

// ---------------------------------------------------------------------------
// GRU scan, pipelined. One wave per (batch, direction).
//   Time processed in 128 chunks of 4 steps. Two register banks g[2][4]
//   alternate per chunk: loads issued in chunk c (into bank c+1&1) are
//   consumed in chunk c+1 — 4-body prefetch distance, and NO register copy
//   ever reads an in-flight load, so the compiler can keep vmcnt > 0.
//   ids/mask: one int4 per chunk, loaded 2-3 chunks ahead, rotated at chunk
//   boundaries only (1-chunk distance).
// ---------------------------------------------------------------------------
template <int USE_IDS>
__global__ __launch_bounds__(64, 1) void gru_scan(
    const float* __restrict__ gi,     // [rows,192]: G0 (gather) or gi1 (direct)
    const int* __restrict__ ids,
    const int* __restrict__ mask,
    const float* __restrict__ Whh_f, const float* __restrict__ Whh_b,
    const float* __restrict__ bhh_f, const float* __restrict__ bhh_b,
    float* __restrict__ out_seq,      // [B,T,64] or nullptr
    float* __restrict__ out_fin)      // [B,64]   or nullptr
{
    const int l = threadIdx.x;
    const int j = l & 31;
    const bool lower = l < 32;
    const int dir = blockIdx.x & 1;
    const int b = blockIdx.x >> 1;
    const int bT = b * T_;

    const float* Whh = dir ? Whh_b : Whh_f;
    const float* bhh = dir ? bhh_b : bhh_f;

    // weight rows -> registers (AGPR/VGPR unified file; VALU reads AGPR free)
    const int rowA = lower ? j : (32 + j);  // r-row (lower) / z-row (upper)
    float wA[32], wB[32];
    #pragma unroll
    for (int q = 0; q < 8; ++q) {
        float4 a = *(const float4*)&Whh[rowA * 32 + q * 4];
        wA[q * 4 + 0] = a.x; wA[q * 4 + 1] = a.y;
        wA[q * 4 + 2] = a.z; wA[q * 4 + 3] = a.w;
        float4 bq = *(const float4*)&Whh[(64 + j) * 32 + q * 4];
        wB[q * 4 + 0] = bq.x; wB[q * 4 + 1] = bq.y;
        wB[q * 4 + 2] = bq.z; wB[q * 4 + 3] = bq.w;
    }
    const float bn = bhh[64 + j];
    const int offA = dir * 96 + l;        // r/z input offset within gi row
    const int offB = dir * 96 + 64 + j;   // n input offset

    // int4 word base for chunk c (fwd: t=4c..4c+3; bwd: t=511-4c..508-4c)
    auto wbase = [&](int c) { return dir ? (bT + 508 - 4 * c) : (bT + 4 * c); };

    // ---- prologue ----
    int4 ids0 = make_int4(0, 0, 0, 0);
    if (USE_IDS) ids0 = *(const int4*)&ids[wbase(0)];
    int4 mask_use = *(const int4*)&mask[wbase(0)];
    int4 mask_mid = *(const int4*)&mask[wbase(1)];
    int4 mask_in  = make_int4(0, 0, 0, 0);
    int4 ids_pf = make_int4(0, 0, 0, 0), ids_mid = ids_pf, ids_in = ids_pf;
    if (USE_IDS) {
        ids_pf  = *(const int4*)&ids[wbase(1)];
        ids_mid = *(const int4*)&ids[wbase(2)];
    }

    float gA[2][4], gB[2][4];
    #pragma unroll
    for (int u = 0; u < 4; ++u) {
        int row;
        if (USE_IDS) {
            const int* ip = (const int*)&ids0;
            row = dir ? ip[3 - u] : ip[u];
        } else {
            row = bT + (dir ? (511 - u) : u);
        }
        const float* gp = gi + (size_t)row * 192;
        gA[0][u] = gp[offA];
        gB[0][u] = gp[offB];
    }

    float h = 0.f;

    for (int c2 = 0; c2 < 64; ++c2) {
        #pragma unroll
        for (int p = 0; p < 2; ++p) {
            const int c = 2 * c2 + p;
            // far prefetch: ids for chunk c+3, mask for chunk c+2 (clamped)
            if (USE_IDS) {
                const int ci = (c + 3 < 128) ? (c + 3) : 127;
                ids_in = *(const int4*)&ids[wbase(ci)];
            }
            {
                const int cm = (c + 2 < 128) ? (c + 2) : 127;
                mask_in = *(const int4*)&mask[wbase(cm)];
            }
            const int cN = (c + 1 < 128) ? (c + 1) : 127;  // gi prefetch chunk

            #pragma unroll
            for (int u = 0; u < 4; ++u) {
                // --- issue gi prefetch for chunk c+1, body u, into bank p^1
                int rowN;
                if (USE_IDS) {
                    const int* ip = (const int*)&ids_pf;
                    rowN = dir ? ip[3 - u] : ip[u];
                } else {
                    rowN = bT + (dir ? (511 - 4 * cN - u) : (4 * cN + u));
                }
                const float* gpN = gi + (size_t)rowN * 192;
                gA[p ^ 1][u] = gpN[offA];
                gB[p ^ 1][u] = gpN[offB];

                // --- compute step (uses bank p, loaded during chunk c-1)
                const int* mu = (const int*)&mask_use;
                const int m = dir ? mu[3 - u] : mu[u];

                float aA0 = 0.f, aA1 = 0.f, aA2 = 0.f, aA3 = 0.f;
                float aB0 = 0.f, aB1 = 0.f, aB2 = 0.f, aB3 = 0.f;
                #pragma unroll
                for (int k = 0; k < 32; k += 4) {
                    const float h0 = rl(h, k);
                    const float h1 = rl(h, k + 1);
                    const float h2 = rl(h, k + 2);
                    const float h3 = rl(h, k + 3);
                    aA0 = fmaf(wA[k],     h0, aA0);  aB0 = fmaf(wB[k],     h0, aB0);
                    aA1 = fmaf(wA[k + 1], h1, aA1);  aB1 = fmaf(wB[k + 1], h1, aB1);
                    aA2 = fmaf(wA[k + 2], h2, aA2);  aB2 = fmaf(wB[k + 2], h2, aB2);
                    aA3 = fmaf(wA[k + 3], h3, aA3);  aB3 = fmaf(wB[k + 3], h3, aB3);
                }
                const float dA = (aA0 + aA1) + (aA2 + aA3);
                const float dB = (aB0 + aB1) + (aB2 + aB3);

                const float s  = sigmoidf_fast(gA[p][u] + dA); // r (lo) / z (hi)
                const float hn = bn + dB;
                const float zz = __shfl_xor(s, 32, 64);        // lo lanes get z
                const float n  = tanhf_fast(gB[p][u] + s * hn);
                const float hnew = n + zz * (h - n);           // (1-z)n + z h
                h = m ? hnew : h;                              // packed-seq freeze

                if (out_seq != nullptr) {
                    const int t = dir ? (511 - 4 * c - u) : (4 * c + u);
                    if (lower)
                        out_seq[(size_t)(bT + t) * 64 + dir * 32 + j] = h;
                }
            }
            // --- rotate chunk-granular prefetch regs (1-chunk distance)
            mask_use = mask_mid; mask_mid = mask_in;
            if (USE_IDS) { ids_pf = ids_mid; ids_mid = ids_in; }
        }
    }

    if (out_fin != nullptr && lower)
        out_fin[b * 64 + dir * 32 + j] = h;
}

// ---------------------------------------------------------------------------
// Head: out[b,o] = hfin[b,:] . Wout[o,:] + bout[o]
// ---------------------------------------------------------------------------
__global__ void head_kernel(const float* __restrict__ hfin,
                            const float* __restrict__ Wout,
                            const float* __restrict__ bout,
                            float* __restrict__ out)
{
    int idx = blockIdx.x * blockDim.x + threadIdx.x;
    if (idx >= B_ * 6) return;
    int b = idx / 6, o = idx % 6;
    float acc = bout[o];
    const float* hp = hfin + b * 64;
    const float* wp = Wout + o * 64;
    #pragma unroll
    for (int k = 0; k < 64; ++k) acc = fmaf(hp[k], wp[k], acc);
    out[idx] = acc;
}

// ---------------------------------------------------------------------------
extern "C" void kernel_launch(void* const* d_in, const int* in_sizes, int n_in,
                              void* d_out, int out_size, void* d_ws, size_t ws_size,
                              hipStream_t stream)
{
    const int*   ids   = (const int*)d_in[0];
    const int*   mask  = (const int*)d_in[1];
    const float* embed = (const float*)d_in[2];
    const float* Wih0f = (const float*)d_in[3];
    const float* Whh0f = (const float*)d_in[4];
    const float* bih0f = (const float*)d_in[5];
    const float* bhh0f = (const float*)d_in[6];
    const float* Wih0b = (const float*)d_in[7];
    const float* Whh0b = (const float*)d_in[8];
    const float* bih0b = (const float*)d_in[9];
    const float* bhh0b = (const float*)d_in[10];
    const float* Wih1f = (const float*)d_in[11];
    const float* Whh1f = (const float*)d_in[12];
    const float* bih1f = (const float*)d_in[13];
    const float* bhh1f = (const float*)d_in[14];
    const float* Wih1b = (const float*)d_in[15];
    const float* Whh1b = (const float*)d_in[16];
    const float* bih1b = (const float*)d_in[17];
    const float* bhh1b = (const float*)d_in[18];
    const float* Wout  = (const float*)d_in[19];
    const float* bout  = (const float*)d_in[20];

    // workspace layout (floats):
    //   gbuf : G0 [V,192] (K1,K2) then gi1 [B*T,192] (K3,K4)
    //   x1   : [B,T,64]
    //   hfin : [B,64]
    float* ws   = (float*)d_ws;
    float* gbuf = ws;
    float* x1   = ws + (size_t)B_ * T_ * 192;
    float* hfin = x1 + (size_t)B_ * T_ * 64;

    // K1: vocab-factored layer-0 input gates  G0 = embed @ Wcat0^T + bias
    gemm_gates<<<(V_ + GEMM_MT - 1) / GEMM_MT, 256, 0, stream>>>(
        embed, V_, E_, Wih0f, Wih0b, bih0f, bhh0f, bih0b, bhh0b, gbuf);

    // K2: layer-0 bidirectional scan (gathers G0[id]), writes x1
    gru_scan<1><<<2 * B_, 64, 0, stream>>>(
        gbuf, ids, mask, Whh0f, Whh0b, bhh0f, bhh0b, x1, nullptr);

    // K3: layer-1 input gates  gi1 = x1 @ Wcat1^T + bias  (overwrites dead G0)
    gemm_gates<<<(B_ * T_) / GEMM_MT, 256, 0, stream>>>(
        x1, B_ * T_, 64, Wih1f, Wih1b, bih1f, bhh1f, bih1b, bhh1b, gbuf);

    // K4: layer-1 scan, final hiddens only
    gru_scan<0><<<2 * B_, 64, 0, stream>>>(
        gbuf, nullptr, mask, Whh1f, Whh1b, bhh1f, bhh1b, nullptr, hfin);

    // K5: output head
    head_kernel<<<(B_ * 6 + 255) / 256, 256, 0, stream>>>(hfin, Wout, bout,
                                                          (float*)d_out);
}

// Round 4
// 563.331 us; speedup vs baseline: 1.2391x; 1.0251x over previous
//
#include <hip/hip_runtime.h>
#include <hip/hip_bf16.h>
#include <stdint.h>

#define B_ 256
#define T_ 512
#define V_ 30000
#define E_ 256
#define H_ 32

typedef float v2f __attribute__((ext_vector_type(2)));

// ---------------------------------------------------------------------------
// Fast activations (fp32, saturate cleanly at extremes: no NaN)
// ---------------------------------------------------------------------------
__device__ __forceinline__ float sigmoidf_fast(float x) {
    return 1.0f / (1.0f + __expf(-x));
}
__device__ __forceinline__ float tanhf_fast(float x) {
    return 1.0f - 2.0f / (1.0f + __expf(2.0f * x));
}
__device__ __forceinline__ uint32_t rlu(float v, int lane) {
    return (uint32_t)__builtin_amdgcn_readlane(__float_as_int(v), lane);
}
// packed fp32 FMA: acc.{lo,hi} += w.{lo,hi} * h{k,k+1}  (h-pair in SGPR pair)
__device__ __forceinline__ void pk_fma(v2f& acc, v2f w, uint64_t hh) {
    asm("v_pk_fma_f32 %0, %1, %2, %0" : "+v"(acc) : "v"(w), "s"(hh));
}

// ---------------------------------------------------------------------------
// GEMM: Out[M,192] = A[M,K] @ Wcat[192,K]^T + bias   (unchanged)
// ---------------------------------------------------------------------------
#define GEMM_MT 64
#define GEMM_KC 32
#define GEMM_PA 68
#define GEMM_PB 196

__global__ __launch_bounds__(256) void gemm_gates(
    const float* __restrict__ A, int M, int K,
    const float* __restrict__ Wf, const float* __restrict__ Wb,
    const float* __restrict__ bihf, const float* __restrict__ bhhf,
    const float* __restrict__ bihb, const float* __restrict__ bhhb,
    float* __restrict__ Out)
{
    __shared__ float As[GEMM_KC][GEMM_PA];
    __shared__ float Bs[GEMM_KC][GEMM_PB];

    const int tid = threadIdx.x;
    const int mbase = blockIdx.x * GEMM_MT;
    const int mg = tid >> 5, ng = tid & 31;
    const int m_off = mg * 8, n_off = ng * 6;

    float acc[8][6];
    #pragma unroll
    for (int r = 0; r < 8; ++r)
        #pragma unroll
        for (int c = 0; c < 6; ++c) acc[r][c] = 0.f;

    for (int kc = 0; kc < K; kc += GEMM_KC) {
        #pragma unroll
        for (int i = 0; i < 2; ++i) {
            int fi = tid + 256 * i;
            int row = fi >> 3, cf = fi & 7;
            int m = mbase + row;
            float4 v = make_float4(0.f, 0.f, 0.f, 0.f);
            if (m < M) v = *(const float4*)&A[(size_t)m * K + kc + cf * 4];
            As[cf * 4 + 0][row] = v.x; As[cf * 4 + 1][row] = v.y;
            As[cf * 4 + 2][row] = v.z; As[cf * 4 + 3][row] = v.w;
        }
        #pragma unroll
        for (int i = 0; i < 6; ++i) {
            int fi = tid + 256 * i;
            int g = fi >> 3, cf = fi & 7;
            const float* Wsel = (g < 96) ? (Wf + (size_t)g * K)
                                         : (Wb + (size_t)(g - 96) * K);
            float4 v = *(const float4*)&Wsel[kc + cf * 4];
            Bs[cf * 4 + 0][g] = v.x; Bs[cf * 4 + 1][g] = v.y;
            Bs[cf * 4 + 2][g] = v.z; Bs[cf * 4 + 3][g] = v.w;
        }
        __syncthreads();
        #pragma unroll
        for (int k = 0; k < GEMM_KC; ++k) {
            float a[8], bb[6];
            *(float4*)&a[0] = *(const float4*)&As[k][m_off];
            *(float4*)&a[4] = *(const float4*)&As[k][m_off + 4];
            *(float2*)&bb[0] = *(const float2*)&Bs[k][n_off];
            *(float2*)&bb[2] = *(const float2*)&Bs[k][n_off + 2];
            *(float2*)&bb[4] = *(const float2*)&Bs[k][n_off + 4];
            #pragma unroll
            for (int r = 0; r < 8; ++r)
                #pragma unroll
                for (int c = 0; c < 6; ++c)
                    acc[r][c] = fmaf(a[r], bb[c], acc[r][c]);
        }
        __syncthreads();
    }

    float bias[6];
    #pragma unroll
    for (int c = 0; c < 6; ++c) {
        int g = n_off + c;
        int g96 = (g < 96) ? g : g - 96;
        const float* bih = (g < 96) ? bihf : bihb;
        const float* bhh = (g < 96) ? bhhf : bhhb;
        bias[c] = bih[g96] + ((g96 < 64) ? bhh[g96] : 0.f);
    }
    #pragma unroll
    for (int r = 0; r < 8; ++r) {
        int m = mbase + m_off + r;
        if (m < M) {
            float* op = &Out[(size_t)m * 192 + n_off];
            #pragma unroll
            for (int c = 0; c < 6; ++c) op[c] = acc[r][c] + bias[c];
        }
    }
}

// ---------------------------------------------------------------------------
// GRU scan. One wave per (batch, direction). h[j] in lane j (j<32); every
// lane computes ALL THREE gates for its unit (upper half redundant) — this
// removes the cross-half __shfl_xor (ds-pipe ~120 cyc) from the h->h critical
// path. Recurrent matvec: 48 v_pk_fma_f32 (96 FMAs) with h broadcast via
// v_readlane -> SGPR-pair (packing rides the scalar pipe).
// gi prefetch: 128 chunks of 4 steps, two register banks alternate per chunk
// (4-body distance, no copy ever reads an in-flight load).
// ---------------------------------------------------------------------------
template <int USE_IDS>
__global__ __launch_bounds__(64, 1) void gru_scan(
    const float* __restrict__ gi,     // [rows,192]: G0 (gather) or gi1 (direct)
    const int* __restrict__ ids,
    const int* __restrict__ mask,
    const float* __restrict__ Whh_f, const float* __restrict__ Whh_b,
    const float* __restrict__ bhh_f, const float* __restrict__ bhh_b,
    float* __restrict__ out_seq,      // [B,T,64] or nullptr
    float* __restrict__ out_fin)      // [B,64]   or nullptr
{
    const int l = threadIdx.x;
    const int j = l & 31;
    const bool lower = l < 32;
    const int dir = blockIdx.x & 1;
    const int b = blockIdx.x >> 1;
    const int bT = b * T_;

    const float* Whh = dir ? Whh_b : Whh_f;
    const float* bhh = dir ? bhh_b : bhh_f;

    // per-lane weight rows (r=j, z=32+j, n=64+j) as fp32 pairs
    v2f wR[16], wZ[16], wN[16];
    #pragma unroll
    for (int q = 0; q < 16; ++q) {
        wR[q] = *(const v2f*)&Whh[j * 32 + 2 * q];
        wZ[q] = *(const v2f*)&Whh[(32 + j) * 32 + 2 * q];
        wN[q] = *(const v2f*)&Whh[(64 + j) * 32 + 2 * q];
    }
    const float bn = bhh[64 + j];

    const int offR = dir * 96 + j;
    const int offZ = dir * 96 + 32 + j;
    const int offN = dir * 96 + 64 + j;

    // int4 word base for chunk c (fwd: t=4c..4c+3; bwd: t=511-4c..508-4c)
    auto wbase = [&](int c) { return dir ? (bT + 508 - 4 * c) : (bT + 4 * c); };

    // ---- prologue ----
    int4 ids0 = make_int4(0, 0, 0, 0);
    if (USE_IDS) ids0 = *(const int4*)&ids[wbase(0)];
    int4 mask_use = *(const int4*)&mask[wbase(0)];
    int4 mask_mid = *(const int4*)&mask[wbase(1)];
    int4 mask_in  = make_int4(0, 0, 0, 0);
    int4 ids_pf = make_int4(0, 0, 0, 0), ids_mid = ids_pf, ids_in = ids_pf;
    if (USE_IDS) {
        ids_pf  = *(const int4*)&ids[wbase(1)];
        ids_mid = *(const int4*)&ids[wbase(2)];
    }

    float gR[2][4], gZ[2][4], gN[2][4];
    #pragma unroll
    for (int u = 0; u < 4; ++u) {
        int row;
        if (USE_IDS) {
            const int* ip = (const int*)&ids0;
            row = dir ? ip[3 - u] : ip[u];
        } else {
            row = bT + (dir ? (511 - u) : u);
        }
        const float* gp = gi + (size_t)row * 192;
        gR[0][u] = gp[offR];
        gZ[0][u] = gp[offZ];
        gN[0][u] = gp[offN];
    }

    float h = 0.f;

    for (int c2 = 0; c2 < 64; ++c2) {
        #pragma unroll
        for (int p = 0; p < 2; ++p) {
            const int c = 2 * c2 + p;
            // far prefetch: ids for chunk c+3, mask for chunk c+2 (clamped)
            if (USE_IDS) {
                const int ci = (c + 3 < 128) ? (c + 3) : 127;
                ids_in = *(const int4*)&ids[wbase(ci)];
            }
            {
                const int cm = (c + 2 < 128) ? (c + 2) : 127;
                mask_in = *(const int4*)&mask[wbase(cm)];
            }
            const int cN = (c + 1 < 128) ? (c + 1) : 127;  // gi prefetch chunk

            #pragma unroll
            for (int u = 0; u < 4; ++u) {
                // --- issue gi prefetch for chunk c+1, body u, into bank p^1
                int rowN;
                if (USE_IDS) {
                    const int* ip = (const int*)&ids_pf;
                    rowN = dir ? ip[3 - u] : ip[u];
                } else {
                    rowN = bT + (dir ? (511 - 4 * cN - u) : (4 * cN + u));
                }
                const float* gpN = gi + (size_t)rowN * 192;
                gR[p ^ 1][u] = gpN[offR];
                gZ[p ^ 1][u] = gpN[offZ];
                gN[p ^ 1][u] = gpN[offN];

                // --- compute step (uses bank p, loaded during chunk c-1)
                const int* mu = (const int*)&mask_use;
                const int m = dir ? mu[3 - u] : mu[u];

                v2f aR = {0.f, 0.f}, aZ = {0.f, 0.f}, aN = {0.f, 0.f};
                #pragma unroll
                for (int k = 0; k < 16; ++k) {
                    const uint32_t hlo = rlu(h, 2 * k);
                    const uint32_t hhi = rlu(h, 2 * k + 1);
                    const uint64_t hh = ((uint64_t)hhi << 32) | hlo;
                    pk_fma(aR, wR[k], hh);
                    pk_fma(aZ, wZ[k], hh);
                    pk_fma(aN, wN[k], hh);
                }
                const float r  = sigmoidf_fast(gR[p][u] + aR.x + aR.y);
                const float z  = sigmoidf_fast(gZ[p][u] + aZ.x + aZ.y);
                const float hn = bn + aN.x + aN.y;
                const float n  = tanhf_fast(gN[p][u] + r * hn);
                const float hnew = n + z * (h - n);      // (1-z)n + z h
                h = m ? hnew : h;                        // packed-seq freeze

                if (out_seq != nullptr) {
                    const int t = dir ? (511 - 4 * c - u) : (4 * c + u);
                    if (lower)
                        out_seq[(size_t)(bT + t) * 64 + dir * 32 + j] = h;
                }
            }
            // --- rotate chunk-granular prefetch regs (1-chunk distance)
            mask_use = mask_mid; mask_mid = mask_in;
            if (USE_IDS) { ids_pf = ids_mid; ids_mid = ids_in; }
        }
    }

    if (out_fin != nullptr && lower)
        out_fin[b * 64 + dir * 32 + j] = h;
}

// ---------------------------------------------------------------------------
// Head: out[b,o] = hfin[b,:] . Wout[o,:] + bout[o]
// ---------------------------------------------------------------------------
__global__ void head_kernel(const float* __restrict__ hfin,
                            const float* __restrict__ Wout,
                            const float* __restrict__ bout,
                            float* __restrict__ out)
{
    int idx = blockIdx.x * blockDim.x + threadIdx.x;
    if (idx >= B_ * 6) return;
    int b = idx / 6, o = idx % 6;
    float acc = bout[o];
    const float* hp = hfin + b * 64;
    const float* wp = Wout + o * 64;
    #pragma unroll
    for (int k = 0; k < 64; ++k) acc = fmaf(hp[k], wp[k], acc);
    out[idx] = acc;
}

// ---------------------------------------------------------------------------
extern "C" void kernel_launch(void* const* d_in, const int* in_sizes, int n_in,
                              void* d_out, int out_size, void* d_ws, size_t ws_size,
                              hipStream_t stream)
{
    const int*   ids   = (const int*)d_in[0];
    const int*   mask  = (const int*)d_in[1];
    const float* embed = (const float*)d_in[2];
    const float* Wih0f = (const float*)d_in[3];
    const float* Whh0f = (const float*)d_in[4];
    const float* bih0f = (const float*)d_in[5];
    const float* bhh0f = (const float*)d_in[6];
    const float* Wih0b = (const float*)d_in[7];
    const float* Whh0b = (const float*)d_in[8];
    const float* bih0b = (const float*)d_in[9];
    const float* bhh0b = (const float*)d_in[10];
    const float* Wih1f = (const float*)d_in[11];
    const float* Whh1f = (const float*)d_in[12];
    const float* bih1f = (const float*)d_in[13];
    const float* bhh1f = (const float*)d_in[14];
    const float* Wih1b = (const float*)d_in[15];
    const float* Whh1b = (const float*)d_in[16];
    const float* bih1b = (const float*)d_in[17];
    const float* bhh1b = (const float*)d_in[18];
    const float* Wout  = (const float*)d_in[19];
    const float* bout  = (const float*)d_in[20];

    // workspace layout (floats):
    //   gbuf : G0 [V,192] (K1,K2) then gi1 [B*T,192] (K3,K4)
    //   x1   : [B,T,64]
    //   hfin : [B,64]
    float* ws   = (float*)d_ws;
    float* gbuf = ws;
    float* x1   = ws + (size_t)B_ * T_ * 192;
    float* hfin = x1 + (size_t)B_ * T_ * 64;

    // K1: vocab-factored layer-0 input gates  G0 = embed @ Wcat0^T + bias
    gemm_gates<<<(V_ + GEMM_MT - 1) / GEMM_MT, 256, 0, stream>>>(
        embed, V_, E_, Wih0f, Wih0b, bih0f, bhh0f, bih0b, bhh0b, gbuf);

    // K2: layer-0 bidirectional scan (gathers G0[id]), writes x1
    gru_scan<1><<<2 * B_, 64, 0, stream>>>(
        gbuf, ids, mask, Whh0f, Whh0b, bhh0f, bhh0b, x1, nullptr);

    // K3: layer-1 input gates  gi1 = x1 @ Wcat1^T + bias  (overwrites dead G0)
    gemm_gates<<<(B_ * T_) / GEMM_MT, 256, 0, stream>>>(
        x1, B_ * T_, 64, Wih1f, Wih1b, bih1f, bhh1f, bih1b, bhh1b, gbuf);

    // K4: layer-1 scan, final hiddens only
    gru_scan<0><<<2 * B_, 64, 0, stream>>>(
        gbuf, nullptr, mask, Whh1f, Whh1b, bhh1f, bhh1b, nullptr, hfin);

    // K5: output head
    head_kernel<<<(B_ * 6 + 255) / 256, 256, 0, stream>>>(hfin, Wout, bout,
                                                          (float*)d_out);
}